// Round 1
// baseline (99.382 us; speedup 1.0000x reference)
//
#include <hip/hip_runtime.h>

// IrrepsIndexedLinear: y_ir[n,o,i] = alpha * sum_m x_ir[n,m,i] * w[seg(n), ir, m, o]
// N=2048 rows, MUL=128 (m and o), dims = {1,3,5}, G=32 groups, alpha = 1/64.
//
// One kernel launch. Blocks are partitioned by irrep with worst-case tile
// capacity; each block scans repeats[] (32 ints, wave-uniform -> scalar unit)
// to find its group-aligned row tile, so tiles never straddle a weight group.
//
// Per block: stage X tile (TR rows x 128 m x d) transposed into LDS as
// Xs[m][slot], slot grouped so each thread's RP r'-rows are contiguous;
// loop 8 m-tiles of 16, staging W[16][128] in LDS (float4 coalesced),
// inner loop: 1 float4 W read + RP scalar X reads (wave-broadcast) ->
// RP*4 FMAs into registers. Epilogue scales by alpha and scatters to the
// (n, o, i) output layout.

#define NROWS 2048
#define NGROUP 32
#define WSTRIDE (128 * 128 * 3) // 49152 floats per group
#define ALPHA 0.015625f         // 1/sqrt(32*128) = 1/64 exactly

// tile capacities: cap_ir = NGROUP + NROWS/TR_ir
// ir0: TR=32 -> 96 ; ir1: TR=16 -> 160 ; ir2: TR=8 -> 288 ; total grid 544
#define CAP0 96
#define CAP01 256 // 96 + 160
#define GRID_BLOCKS 544

template <int D, int TR, int RP, int SS>
__device__ inline void run_ir(int lt, const float* __restrict__ x,
                              const float* __restrict__ w_base_ir, // w + ir_woff
                              const int* __restrict__ repeats,
                              float* __restrict__ obase, // out + ir out offset
                              float (*Xs)[64], float (*Ws)[128]) {
  // ---- group-aligned tile lookup (uniform across block) ----
  int off = 0, g = -1, row0 = 0, nr = 0;
  int tacc = 0;
  for (int gg = 0; gg < NGROUP; ++gg) {
    int c = repeats[gg];
    int tg = (c + TR - 1) / TR;
    if (lt < tacc + tg) {
      int tig = lt - tacc;
      g = gg;
      row0 = off + tig * TR;
      nr = min(TR, c - tig * TR);
      break;
    }
    tacc += tg;
    off += c;
  }
  if (g < 0) return; // beyond real tile count for this irrep

  const int tid = threadIdx.x;
  const int to = tid & 31; // o-group: owns o = to*4 .. to*4+3
  const int tr = tid >> 5; // r'-group: owns r' = tr*RP .. tr*RP+RP-1

  // ---- stage X tile into LDS, transposed to Xs[m][slot] ----
  // r' = n_loc*D + i ; slot = (r'/RP)*SS + (r'%RP)
  constexpr int ROWELEMS = 128 * D;
  constexpr int BMELEMS = TR * ROWELEMS;
  const float* xrow = x + (size_t)row0 * ROWELEMS;
  for (int idx = tid; idx < BMELEMS; idx += 256) {
    int n_loc = idx / ROWELEMS;
    int rem = idx - n_loc * ROWELEMS;
    int m = rem / D;
    int i = rem - m * D;
    int rp = n_loc * D + i;
    int trp = rp / RP;
    int offp = rp - trp * RP;
    float v = 0.0f;
    if (n_loc < nr) v = xrow[idx]; // guarded: partial tiles must not read OOB
    Xs[m][trp * SS + offp] = v;
  }

  const float* w_g = w_base_ir + (size_t)g * WSTRIDE;

  float acc[RP][4];
#pragma unroll
  for (int rr = 0; rr < RP; ++rr)
#pragma unroll
    for (int oj = 0; oj < 4; ++oj) acc[rr][oj] = 0.0f;

  // ---- K loop: 8 m-tiles of 16 ----
  for (int mt = 0; mt < 8; ++mt) {
    __syncthreads(); // X ready (mt=0) / previous tile's compute done
    {
      const float4* wsrc = (const float4*)(w_g + mt * 16 * 128);
      float4* wdst = (float4*)Ws;
      for (int idx = tid; idx < 512; idx += 256) wdst[idx] = wsrc[idx];
    }
    __syncthreads();
#pragma unroll
    for (int ml = 0; ml < 16; ++ml) {
      const int m = mt * 16 + ml;
      const float4 wf = *(const float4*)&Ws[ml][to * 4];
      float xs[RP];
#pragma unroll
      for (int rr = 0; rr < RP; ++rr) xs[rr] = Xs[m][tr * SS + rr];
#pragma unroll
      for (int rr = 0; rr < RP; ++rr) {
        acc[rr][0] += xs[rr] * wf.x;
        acc[rr][1] += xs[rr] * wf.y;
        acc[rr][2] += xs[rr] * wf.z;
        acc[rr][3] += xs[rr] * wf.w;
      }
    }
  }

  // ---- epilogue: y[n, o, i] ----
#pragma unroll
  for (int rr = 0; rr < RP; ++rr) {
    int rp = tr * RP + rr;
    int n_loc = rp / D;
    int i = rp - n_loc * D;
    if (n_loc < nr) {
      float* orow = obase + (size_t)(row0 + n_loc) * ROWELEMS + i;
#pragma unroll
      for (int oj = 0; oj < 4; ++oj) orow[(to * 4 + oj) * D] = acc[rr][oj] * ALPHA;
    }
  }
}

__global__ __launch_bounds__(256) void IrrepsIndexedLinear_39161511805249_kernel(
    const float* __restrict__ x0, const float* __restrict__ x1,
    const float* __restrict__ x2, const float* __restrict__ w,
    const int* __restrict__ repeats, float* __restrict__ out) {
  __shared__ float Xs[128][64]; // 32 KB
  __shared__ float Ws[16][128]; // 8 KB

  const int bid = blockIdx.x;
  if (bid < CAP0) {
    // ir0: d=1, TR=32, RP=4, SS=4 ; w offset 0 ; out offset 0
    run_ir<1, 32, 4, 4>(bid, x0, w, repeats, out, Xs, Ws);
  } else if (bid < CAP01) {
    // ir1: d=3, TR=16, RP=6, SS=8 ; w offset 16384 ; out offset 2048*128
    run_ir<3, 16, 6, 8>(bid - CAP0, x1, w + 16384, repeats, out + 262144, Xs, Ws);
  } else {
    // ir2: d=5, TR=8, RP=5, SS=8 ; w offset 32768 ; out offset 2048*128*4
    run_ir<5, 8, 5, 8>(bid - CAP01, x2, w + 32768, repeats, out + 1048576, Xs, Ws);
  }
}

extern "C" void kernel_launch(void* const* d_in, const int* in_sizes, int n_in,
                              void* d_out, int out_size, void* d_ws, size_t ws_size,
                              hipStream_t stream) {
  const float* x0 = (const float*)d_in[0];
  const float* x1 = (const float*)d_in[1];
  const float* x2 = (const float*)d_in[2];
  const float* w = (const float*)d_in[3];
  const int* repeats = (const int*)d_in[4];
  float* out = (float*)d_out;

  IrrepsIndexedLinear_39161511805249_kernel<<<GRID_BLOCKS, 256, 0, stream>>>(
      x0, x1, x2, w, repeats, out);
}

// Round 2
// 94.286 us; speedup vs baseline: 1.0540x; 1.0540x over previous
//
#include <hip/hip_runtime.h>

// IrrepsIndexedLinear: y_ir[n,o,i] = alpha * sum_m x_ir[n,m,i] * w[seg(n), ir, m, o]
// N=2048 rows, MUL=128 (m and o), dims = {1,3,5}, G=32 groups, alpha = 1/64.
//
// Round-2 structure:
//  - group-aligned row tiles per block (scan repeats[], wave-uniform)
//  - X tile staged RAW into LDS (straight float4 copy: coalesced global reads,
//    conflict-free LDS writes, no integer division)
//  - W is NOT staged: each thread owns output columns to*4..to*4+3 and streams
//    w_g[m*128 + to*4] as float4 directly from global (coalesced across the
//    wave, L1/L2-resident: 64 KB per group reused 8x within the block).
//    => zero barriers in the K-loop (round 1 had 16).
//  - inner loop per m: 1 global b128 (W) + RP LDS b32 broadcasts (X) + 4*RP FMA
//  - single __syncthreads per block (after X staging).

#define NGROUP 32
#define WSTRIDE (128 * 128 * 3) // floats per weight group
#define ALPHA 0.015625f         // 1/sqrt(32*128) = 1/64 exactly

// tile capacities: cap_ir = NGROUP + NROWS/TR_ir
// ir0: TR=32 -> 96 ; ir1: TR=16 -> 160 ; ir2: TR=8 -> 288 ; total grid 544
#define CAP0 96
#define CAP01 256
#define GRID_BLOCKS 544

#define LDS_FLOATS 6144 // max of TR*128*D: ir1 = 16*384 = 6144 (24 KB)

template <int D, int TR, int RP>
__device__ inline void run_ir(int lt, const float* __restrict__ x,
                              const float* __restrict__ w_base_ir, // w + ir off
                              const int* __restrict__ repeats,
                              float* __restrict__ obase, // out + ir out offset
                              float* __restrict__ Xs) {
  // ---- group-aligned tile lookup (uniform across block) ----
  int off = 0, g = -1, row0 = 0, nr = 0;
  int tacc = 0;
  for (int gg = 0; gg < NGROUP; ++gg) {
    int c = repeats[gg];
    int tg = (c + TR - 1) / TR;
    if (lt < tacc + tg) {
      int tig = lt - tacc;
      g = gg;
      row0 = off + tig * TR;
      nr = min(TR, c - tig * TR);
      break;
    }
    tacc += tg;
    off += c;
  }
  if (g < 0) return; // beyond real tile count for this irrep (whole block)

  const int tid = threadIdx.x;
  const int to = tid & 31; // owns out columns o = to*4 .. to*4+3
  const int tr = tid >> 5; // owns flat rows r = tr*RP .. tr*RP+RP-1

  constexpr int ROWELEMS = 128 * D;
  constexpr int BMELEMS = TR * ROWELEMS;

  // ---- stage X tile raw into LDS (straight copy; zero-fill past nr) ----
  {
    const float4* xsrc = (const float4*)(x + (size_t)row0 * ROWELEMS);
    float4* xdst = (float4*)Xs;
    const int limit4 = nr * (ROWELEMS / 4);
    constexpr int Q = BMELEMS / 4;
    const float4 z = make_float4(0.f, 0.f, 0.f, 0.f);
    for (int q = tid; q < Q; q += 256) xdst[q] = (q < limit4) ? xsrc[q] : z;
  }
  __syncthreads();

  // ---- per-thread row constants: r = tr*RP + rr -> (n_loc, i) ----
  int xoff[RP];
  int nloc[RP];
  int iofr[RP];
#pragma unroll
  for (int rr = 0; rr < RP; ++rr) {
    int r = tr * RP + rr;
    int nl = r / D;
    int i = r - nl * D;
    nloc[rr] = nl;
    iofr[rr] = i;
    xoff[rr] = nl * ROWELEMS + i;
  }

  const float* w_g = w_base_ir + (size_t)g * WSTRIDE;
  const float4* wp = (const float4*)w_g + to; // stride per m: 32 float4s

  float acc[RP][4];
#pragma unroll
  for (int rr = 0; rr < RP; ++rr)
#pragma unroll
    for (int oj = 0; oj < 4; ++oj) acc[rr][oj] = 0.0f;

  // ---- K loop: no barriers; W streamed from global, X broadcast from LDS --
#pragma unroll 8
  for (int m = 0; m < 128; ++m) {
    const float4 wf = wp[m * 32];
    float xs[RP];
#pragma unroll
    for (int rr = 0; rr < RP; ++rr) xs[rr] = Xs[xoff[rr] + m * D];
#pragma unroll
    for (int rr = 0; rr < RP; ++rr) {
      acc[rr][0] += xs[rr] * wf.x;
      acc[rr][1] += xs[rr] * wf.y;
      acc[rr][2] += xs[rr] * wf.z;
      acc[rr][3] += xs[rr] * wf.w;
    }
  }

  // ---- epilogue: y[n, o, i] ----
#pragma unroll
  for (int rr = 0; rr < RP; ++rr) {
    if (nloc[rr] < nr) {
      float* orow = obase + (size_t)(row0 + nloc[rr]) * ROWELEMS + iofr[rr];
#pragma unroll
      for (int oj = 0; oj < 4; ++oj)
        orow[(to * 4 + oj) * D] = acc[rr][oj] * ALPHA;
    }
  }
}

__global__ __launch_bounds__(256) void IrrepsIndexedLinear_39161511805249_kernel(
    const float* __restrict__ x0, const float* __restrict__ x1,
    const float* __restrict__ x2, const float* __restrict__ w,
    const int* __restrict__ repeats, float* __restrict__ out) {
  __shared__ float Xs[LDS_FLOATS]; // 24 KB

  const int bid = blockIdx.x;
  if (bid < CAP0) {
    // ir0: d=1, TR=32, RP=4 ; w offset 0 ; out offset 0
    run_ir<1, 32, 4>(bid, x0, w, repeats, out, Xs);
  } else if (bid < CAP01) {
    // ir1: d=3, TR=16, RP=6 ; w offset 16384 ; out offset 2048*128
    run_ir<3, 16, 6>(bid - CAP0, x1, w + 16384, repeats, out + 262144, Xs);
  } else {
    // ir2: d=5, TR=8, RP=5 ; w offset 32768 ; out offset 2048*128*4
    run_ir<5, 8, 5>(bid - CAP01, x2, w + 32768, repeats, out + 1048576, Xs);
  }
}

extern "C" void kernel_launch(void* const* d_in, const int* in_sizes, int n_in,
                              void* d_out, int out_size, void* d_ws, size_t ws_size,
                              hipStream_t stream) {
  const float* x0 = (const float*)d_in[0];
  const float* x1 = (const float*)d_in[1];
  const float* x2 = (const float*)d_in[2];
  const float* w = (const float*)d_in[3];
  const int* repeats = (const int*)d_in[4];
  float* out = (float*)d_out;

  IrrepsIndexedLinear_39161511805249_kernel<<<GRID_BLOCKS, 256, 0, stream>>>(
      x0, x1, x2, w, repeats, out);
}